// Round 2
// baseline (2952.319 us; speedup 1.0000x reference)
//
#include <hip/hip_runtime.h>
#include <math.h>

#define NN 50000
#define NE 1000000

// ---------------- GEMM: C[M,64] = A[M,K] @ B[K,64], fp32 ----------------
__global__ __launch_bounds__(256) void gemm64(const float* __restrict__ A,
        const float* __restrict__ B, float* __restrict__ C, int M, int K)
{
    __shared__ float As[16][65];   // [kk][row], padded -> conflict-free
    __shared__ float Bs[16][64];   // [kk][col]
    const int tid = threadIdx.x;
    const int row0 = blockIdx.x * 64;
    const int tx = tid & 15, ty = tid >> 4;
    float acc[4][4] = {};
    for (int k0 = 0; k0 < K; k0 += 16) {
        #pragma unroll
        for (int i = 0; i < 4; ++i) {
            int idx = tid + i * 256;
            int r = idx >> 4, kk = idx & 15;
            int gr = row0 + r, gk = k0 + kk;
            float v = 0.f;
            if (gr < M && gk < K) v = A[(size_t)gr * K + gk];
            As[kk][r] = v;
        }
        #pragma unroll
        for (int i = 0; i < 4; ++i) {
            int idx = tid + i * 256;
            int kk = idx >> 6, c = idx & 63;
            int gk = k0 + kk;
            Bs[kk][c] = (gk < K) ? B[(size_t)gk * 64 + c] : 0.f;
        }
        __syncthreads();
        #pragma unroll
        for (int kk = 0; kk < 16; ++kk) {
            float a[4], b[4];
            #pragma unroll
            for (int i = 0; i < 4; ++i) a[i] = As[kk][ty * 4 + i];
            #pragma unroll
            for (int j = 0; j < 4; ++j) b[j] = Bs[kk][tx * 4 + j];
            #pragma unroll
            for (int i = 0; i < 4; ++i)
                #pragma unroll
                for (int j = 0; j < 4; ++j)
                    acc[i][j] += a[i] * b[j];
        }
        __syncthreads();
    }
    #pragma unroll
    for (int i = 0; i < 4; ++i) {
        int r = row0 + ty * 4 + i;
        if (r < M) {
            #pragma unroll
            for (int j = 0; j < 4; ++j)
                C[(size_t)r * 64 + tx * 4 + j] = acc[i][j];
        }
    }
}

// ------------- per-node logit halves, layer1 (H=8, C=8) -------------
__global__ __launch_bounds__(256) void s_l1(const float* __restrict__ h,
        const float* __restrict__ a_src, const float* __restrict__ a_dst,
        float* __restrict__ s_src, float* __restrict__ s_dst)
{
    int t = blockIdx.x * 256 + threadIdx.x;   // t = n*8 + head
    if (t >= NN * 8) return;
    int n = t >> 3, hd = t & 7;
    const float* hp = h + (size_t)n * 64 + hd * 8;
    float ss = 0.f, sd = 0.f;
    #pragma unroll
    for (int c = 0; c < 8; ++c) {
        float v = hp[c];
        ss += v * a_src[hd * 8 + c];
        sd += v * a_dst[hd * 8 + c];
    }
    s_src[t] = ss;
    s_dst[t] = sd;
}

// ------------- per-node logit halves, layer2 (H=1, C=64): wave/node -------------
__global__ __launch_bounds__(256) void s_l2(const float* __restrict__ h,
        const float* __restrict__ a_src, const float* __restrict__ a_dst,
        float* __restrict__ s_src, float* __restrict__ s_dst)
{
    int gid = blockIdx.x * 256 + threadIdx.x;
    int n = gid >> 6;
    int lane = threadIdx.x & 63;
    if (n >= NN) return;
    float v = h[(size_t)n * 64 + lane];
    float ps = v * a_src[lane];
    float pd = v * a_dst[lane];
    #pragma unroll
    for (int off = 32; off > 0; off >>= 1) {
        ps += __shfl_down(ps, off);
        pd += __shfl_down(pd, off);
    }
    if (lane == 0) { s_src[n] = ps; s_dst[n] = pd; }
}

// ------------- edge pass layer1: thread per (edge, head) -------------
__global__ __launch_bounds__(256) void edge_l1(const int* __restrict__ ei,
        const float* __restrict__ h, const float* __restrict__ s_src,
        const float* __restrict__ s_dst, float* __restrict__ numer,
        float* __restrict__ denom)
{
    int t = blockIdx.x * 256 + threadIdx.x;   // t = e*8 + head
    if (t >= NE * 8) return;
    int e = t >> 3, hd = t & 7;
    int src = ei[e];
    int dst = ei[NE + e];
    float s = s_src[src * 8 + hd] + s_dst[dst * 8 + hd];
    s = s > 0.f ? s : 0.2f * s;          // LeakyReLU(0.2)
    float w = __expf(s);                  // no max-shift needed (bounded logits)
    atomicAdd(&denom[dst * 8 + hd], w);
    const float* hp = h + (size_t)src * 64 + hd * 8;
    float* np = numer + (size_t)dst * 64 + hd * 8;
    #pragma unroll
    for (int c = 0; c < 8; ++c)
        atomicAdd(&np[c], w * hp[c]);
}

// ------------- finalize layer1: normalize + bias + ELU -------------
__global__ __launch_bounds__(256) void fin_l1(const float* __restrict__ numer,
        const float* __restrict__ denom, const float* __restrict__ b,
        float* __restrict__ out)
{
    int t = blockIdx.x * 256 + threadIdx.x;   // t = n*64 + j
    if (t >= NN * 64) return;
    int n = t >> 6, j = t & 63, hd = j >> 3;
    float d = denom[n * 8 + hd] + 1e-16f;
    float v = numer[t] / d + b[j];
    out[t] = v > 0.f ? v : expm1f(v);         // ELU(alpha=1)
}

// ------------- edge pass layer2: thread per (edge, 4-channel group) -------------
__global__ __launch_bounds__(256) void edge_l2(const int* __restrict__ ei,
        const float* __restrict__ h, const float* __restrict__ s_src,
        const float* __restrict__ s_dst, float* __restrict__ numer,
        float* __restrict__ denom)
{
    int t = blockIdx.x * 256 + threadIdx.x;   // t = e*16 + q
    if (t >= NE * 16) return;
    int e = t >> 4, q = t & 15;
    int src = ei[e];
    int dst = ei[NE + e];
    float s = s_src[src] + s_dst[dst];
    s = s > 0.f ? s : 0.2f * s;
    float w = __expf(s);
    if (q == 0) atomicAdd(&denom[dst], w);
    const float4 hv = *(const float4*)(h + (size_t)src * 64 + q * 4);
    float* np = numer + (size_t)dst * 64 + q * 4;
    atomicAdd(&np[0], w * hv.x);
    atomicAdd(&np[1], w * hv.y);
    atomicAdd(&np[2], w * hv.z);
    atomicAdd(&np[3], w * hv.w);
}

// ------------- finalize layer2: normalize + bias -> d_out -------------
__global__ __launch_bounds__(256) void fin_l2(const float* __restrict__ numer,
        const float* __restrict__ denom, const float* __restrict__ b,
        float* __restrict__ out)
{
    int t = blockIdx.x * 256 + threadIdx.x;   // t = n*64 + c
    if (t >= NN * 64) return;
    int n = t >> 6, c = t & 63;
    out[t] = numer[t] / (denom[n] + 1e-16f) + b[c];
}

extern "C" void kernel_launch(void* const* d_in, const int* in_sizes, int n_in,
                              void* d_out, int out_size, void* d_ws, size_t ws_size,
                              hipStream_t stream)
{
    const float* x      = (const float*)d_in[0];
    const int*   ei     = (const int*)d_in[1];     // int32 per harness convention
    const float* W1     = (const float*)d_in[2];
    const float* a_src1 = (const float*)d_in[3];
    const float* a_dst1 = (const float*)d_in[4];
    const float* b1     = (const float*)d_in[5];
    const float* W2     = (const float*)d_in[6];
    const float* a_src2 = (const float*)d_in[7];
    const float* a_dst2 = (const float*)d_in[8];
    const float* b2     = (const float*)d_in[9];
    float* out = (float*)d_out;

    // workspace layout with aliasing (peak 31.2 MB):
    //   P0: h1 -> h2in -> numer2    P1: numer1 -> h2
    float* w = (float*)d_ws;
    float* P0     = w;  w += (size_t)NN * 64;
    float* P1     = w;  w += (size_t)NN * 64;
    float* ss1    = w;  w += (size_t)NN * 8;
    float* sd1    = w;  w += (size_t)NN * 8;
    float* denom1 = w;  w += (size_t)NN * 8;
    float* denom2 = w;  w += (size_t)NN;       // adjacent to denom1: one memset
    float* ss2    = w;  w += (size_t)NN;
    float* sd2    = w;  w += (size_t)NN;

    // zero accumulators: numer1 (P1) and denom1+denom2
    hipMemsetAsync(P1, 0, (size_t)NN * 64 * sizeof(float), stream);
    hipMemsetAsync(denom1, 0, (size_t)NN * 9 * sizeof(float), stream);

    // ---- layer 1 ----
    gemm64<<<(NN + 63) / 64, 256, 0, stream>>>(x, W1, P0, NN, 300);        // h1 = P0
    s_l1<<<(NN * 8 + 255) / 256, 256, 0, stream>>>(P0, a_src1, a_dst1, ss1, sd1);
    edge_l1<<<(NE * 8 + 255) / 256, 256, 0, stream>>>(ei, P0, ss1, sd1, P1, denom1);
    fin_l1<<<(NN * 64 + 255) / 256, 256, 0, stream>>>(P1, denom1, b1, P0); // h2in = P0 (h1 dead)

    // ---- layer 2 ----
    gemm64<<<(NN + 63) / 64, 256, 0, stream>>>(P0, W2, P1, NN, 64);        // h2 = P1 (numer1 dead)
    s_l2<<<(NN * 64 + 255) / 256, 256, 0, stream>>>(P1, a_src2, a_dst2, ss2, sd2);
    hipMemsetAsync(P0, 0, (size_t)NN * 64 * sizeof(float), stream);        // numer2 = P0 (h2in dead)
    edge_l2<<<(NE * 16 + 255) / 256, 256, 0, stream>>>(ei, P1, ss2, sd2, P0, denom2);
    fin_l2<<<(NN * 64 + 255) / 256, 256, 0, stream>>>(P0, denom2, b2, out);
}

// Round 3
// 611.599 us; speedup vs baseline: 4.8272x; 4.8272x over previous
//
#include <hip/hip_runtime.h>
#include <math.h>

#define NN 50000
#define NE 1000000

// ---------------- GEMM: C[M,64] = A[M,K] @ B[K,64], fp32 ----------------
__global__ __launch_bounds__(256) void gemm64(const float* __restrict__ A,
        const float* __restrict__ B, float* __restrict__ C, int M, int K)
{
    __shared__ float As[16][65];   // [kk][row], padded -> conflict-free
    __shared__ float Bs[16][64];   // [kk][col]
    const int tid = threadIdx.x;
    const int row0 = blockIdx.x * 64;
    const int tx = tid & 15, ty = tid >> 4;
    float acc[4][4] = {};
    for (int k0 = 0; k0 < K; k0 += 16) {
        #pragma unroll
        for (int i = 0; i < 4; ++i) {
            int idx = tid + i * 256;
            int r = idx >> 4, kk = idx & 15;
            int gr = row0 + r, gk = k0 + kk;
            float v = 0.f;
            if (gr < M && gk < K) v = A[(size_t)gr * K + gk];
            As[kk][r] = v;
        }
        #pragma unroll
        for (int i = 0; i < 4; ++i) {
            int idx = tid + i * 256;
            int kk = idx >> 6, c = idx & 63;
            int gk = k0 + kk;
            Bs[kk][c] = (gk < K) ? B[(size_t)gk * 64 + c] : 0.f;
        }
        __syncthreads();
        #pragma unroll
        for (int kk = 0; kk < 16; ++kk) {
            float a[4], b[4];
            #pragma unroll
            for (int i = 0; i < 4; ++i) a[i] = As[kk][ty * 4 + i];
            #pragma unroll
            for (int j = 0; j < 4; ++j) b[j] = Bs[kk][tx * 4 + j];
            #pragma unroll
            for (int i = 0; i < 4; ++i)
                #pragma unroll
                for (int j = 0; j < 4; ++j)
                    acc[i][j] += a[i] * b[j];
        }
        __syncthreads();
    }
    #pragma unroll
    for (int i = 0; i < 4; ++i) {
        int r = row0 + ty * 4 + i;
        if (r < M) {
            #pragma unroll
            for (int j = 0; j < 4; ++j)
                C[(size_t)r * 64 + tx * 4 + j] = acc[i][j];
        }
    }
}

// ------------- CSR build: in-degree count -------------
__global__ __launch_bounds__(256) void count_k(const int* __restrict__ ei,
        int* __restrict__ cnt)
{
    int e = blockIdx.x * 256 + threadIdx.x;
    if (e < NE) atomicAdd(&cnt[ei[NE + e]], 1);
}

// ------------- CSR build: single-block exclusive scan over NN -------------
__global__ __launch_bounds__(1024) void scan_k(const int* __restrict__ cnt,
        int* __restrict__ rowptr, int* __restrict__ cursor)
{
    __shared__ int buf[1024];
    __shared__ int carry_s;
    int tid = threadIdx.x;
    if (tid == 0) carry_s = 0;
    __syncthreads();
    for (int base = 0; base < NN; base += 1024) {
        int i = base + tid;
        int v = (i < NN) ? cnt[i] : 0;
        buf[tid] = v;
        __syncthreads();
        #pragma unroll
        for (int off = 1; off < 1024; off <<= 1) {
            int t = (tid >= off) ? buf[tid - off] : 0;
            __syncthreads();
            buf[tid] += t;
            __syncthreads();
        }
        int incl = buf[tid];
        int carry = carry_s;
        if (i < NN) { int e = carry + incl - v; rowptr[i] = e; cursor[i] = e; }
        __syncthreads();
        if (tid == 1023) carry_s = carry + incl;
        __syncthreads();
    }
    if (tid == 0) rowptr[NN] = NE;
}

// ------------- CSR build: scatter src into dst-sorted order -------------
__global__ __launch_bounds__(256) void scatter_k(const int* __restrict__ ei,
        int* __restrict__ cursor, int* __restrict__ col)
{
    int e = blockIdx.x * 256 + threadIdx.x;
    if (e < NE) {
        int s = ei[e], d = ei[NE + e];
        int pos = atomicAdd(&cursor[d], 1);
        col[pos] = s;
    }
}

// ------------- per-node logit halves, layer1 (H=8, C=8) -------------
__global__ __launch_bounds__(256) void s_l1(const float* __restrict__ h,
        const float* __restrict__ a_src, const float* __restrict__ a_dst,
        float* __restrict__ s_src, float* __restrict__ s_dst)
{
    int t = blockIdx.x * 256 + threadIdx.x;   // t = n*8 + head
    if (t >= NN * 8) return;
    int n = t >> 3, hd = t & 7;
    const float* hp = h + (size_t)n * 64 + hd * 8;
    float ss = 0.f, sd = 0.f;
    #pragma unroll
    for (int c = 0; c < 8; ++c) {
        float v = hp[c];
        ss += v * a_src[hd * 8 + c];
        sd += v * a_dst[hd * 8 + c];
    }
    s_src[t] = ss;
    s_dst[t] = sd;
}

// ------------- per-node logit halves, layer2 (H=1, C=64) -------------
__global__ __launch_bounds__(256) void s_l2(const float* __restrict__ h,
        const float* __restrict__ a_src, const float* __restrict__ a_dst,
        float* __restrict__ s_src, float* __restrict__ s_dst)
{
    int gid = blockIdx.x * 256 + threadIdx.x;
    int n = gid >> 6;
    int lane = threadIdx.x & 63;
    if (n >= NN) return;
    float v = h[(size_t)n * 64 + lane];
    float ps = v * a_src[lane];
    float pd = v * a_dst[lane];
    #pragma unroll
    for (int off = 32; off > 0; off >>= 1) {
        ps += __shfl_down(ps, off);
        pd += __shfl_down(pd, off);
    }
    if (lane == 0) { s_src[n] = ps; s_dst[n] = pd; }
}

// ------------- layer1 aggregation: one wave per dst node, atomic-free -------------
// lane = output channel (hd = lane>>3); fused normalize + bias + ELU
__global__ __launch_bounds__(256) void agg_l1(const int* __restrict__ rowptr,
        const int* __restrict__ col, const float* __restrict__ h,
        const float* __restrict__ ss, const float* __restrict__ sd,
        const float* __restrict__ b, float* __restrict__ out)
{
    int n = (blockIdx.x * 256 + threadIdx.x) >> 6;   // wave id = node
    int lane = threadIdx.x & 63;
    if (n >= NN) return;
    int hd = lane >> 3;
    float sdst = sd[n * 8 + hd];
    int r0 = rowptr[n], r1 = rowptr[n + 1];
    float acc = 0.f, dsum = 0.f;
    for (int i = r0; i < r1; ++i) {
        int src = col[i];                            // wave-uniform -> scalar load
        float s = ss[src * 8 + hd] + sdst;
        s = s > 0.f ? s : 0.2f * s;                  // LeakyReLU(0.2)
        float w = __expf(s);
        acc += w * h[(size_t)src * 64 + lane];       // coalesced 256B per edge
        dsum += w;
    }
    float v = acc / (dsum + 1e-16f) + b[lane];
    out[(size_t)n * 64 + lane] = v > 0.f ? v : expm1f(v);   // ELU
}

// ------------- layer2 aggregation: one wave per dst node -------------
__global__ __launch_bounds__(256) void agg_l2(const int* __restrict__ rowptr,
        const int* __restrict__ col, const float* __restrict__ h,
        const float* __restrict__ ss, const float* __restrict__ sd,
        const float* __restrict__ b, float* __restrict__ out)
{
    int n = (blockIdx.x * 256 + threadIdx.x) >> 6;
    int lane = threadIdx.x & 63;
    if (n >= NN) return;
    float sdst = sd[n];
    int r0 = rowptr[n], r1 = rowptr[n + 1];
    float acc = 0.f, dsum = 0.f;
    for (int i = r0; i < r1; ++i) {
        int src = col[i];
        float s = ss[src] + sdst;
        s = s > 0.f ? s : 0.2f * s;
        float w = __expf(s);
        acc += w * h[(size_t)src * 64 + lane];
        dsum += w;
    }
    out[(size_t)n * 64 + lane] = acc / (dsum + 1e-16f) + b[lane];
}

extern "C" void kernel_launch(void* const* d_in, const int* in_sizes, int n_in,
                              void* d_out, int out_size, void* d_ws, size_t ws_size,
                              hipStream_t stream)
{
    const float* x      = (const float*)d_in[0];
    const int*   ei     = (const int*)d_in[1];     // int32 per harness convention
    const float* W1     = (const float*)d_in[2];
    const float* a_src1 = (const float*)d_in[3];
    const float* a_dst1 = (const float*)d_in[4];
    const float* b1     = (const float*)d_in[5];
    const float* W2     = (const float*)d_in[6];
    const float* a_src2 = (const float*)d_in[7];
    const float* a_dst2 = (const float*)d_in[8];
    const float* b2     = (const float*)d_in[9];
    float* out = (float*)d_out;

    // workspace (peak ~34 MB): P0 = h1 -> h2, P1 = h2in
    float* w = (float*)d_ws;
    float* P0     = w;  w += (size_t)NN * 64;       // h1, then h2
    float* P1     = w;  w += (size_t)NN * 64;       // h2in (ELU(layer1))
    float* ss1    = w;  w += (size_t)NN * 8;        // reused as ss2/sd2 in layer2
    float* sd1    = w;  w += (size_t)NN * 8;
    int* cnt    = (int*)w;  w += NN;
    int* rowptr = (int*)w;  w += NN + 1;
    int* cursor = (int*)w;  w += NN;
    int* col    = (int*)w;  w += NE;
    float* ss2 = ss1;                                // alias (ss1 dead in layer2)
    float* sd2 = ss1 + NN;

    // ---- CSR build (shared by both layers) ----
    hipMemsetAsync(cnt, 0, NN * sizeof(int), stream);
    count_k<<<(NE + 255) / 256, 256, 0, stream>>>(ei, cnt);
    scan_k<<<1, 1024, 0, stream>>>(cnt, rowptr, cursor);
    scatter_k<<<(NE + 255) / 256, 256, 0, stream>>>(ei, cursor, col);

    // ---- layer 1 ----
    gemm64<<<(NN + 63) / 64, 256, 0, stream>>>(x, W1, P0, NN, 300);         // h1
    s_l1<<<(NN * 8 + 255) / 256, 256, 0, stream>>>(P0, a_src1, a_dst1, ss1, sd1);
    agg_l1<<<(NN * 64 + 255) / 256, 256, 0, stream>>>(rowptr, col, P0, ss1, sd1, b1, P1);

    // ---- layer 2 ----
    gemm64<<<(NN + 63) / 64, 256, 0, stream>>>(P1, W2, P0, NN, 64);         // h2 (h1 dead)
    s_l2<<<(NN * 64 + 255) / 256, 256, 0, stream>>>(P0, a_src2, a_dst2, ss2, sd2);
    agg_l2<<<(NN * 64 + 255) / 256, 256, 0, stream>>>(rowptr, col, P0, ss2, sd2, b2, out);
}

// Round 4
// 393.927 us; speedup vs baseline: 7.4946x; 1.5526x over previous
//
#include <hip/hip_runtime.h>
#include <math.h>

#define NN 50000
#define NE 1000000

// ---------------- GEMM: C[M,64] = A[M,K] @ B[K,64], fp32, 128x64 tile ----------------
__global__ __launch_bounds__(256) void gemm128(const float* __restrict__ A,
        const float* __restrict__ B, float* __restrict__ C, int M, int K)
{
    __shared__ float As[16][132];   // [kk][row], stride 132 -> <=2-way (free) on staging
    __shared__ float Bs[16][64];    // [kk][col]
    const int tid = threadIdx.x;
    const int row0 = blockIdx.x * 128;
    const int tx = tid & 15, ty = tid >> 4;   // tx: 4-col group, ty: 8-row group
    float acc[8][4] = {};
    const int ktiles = (K + 15) / 16;
    for (int t = 0; t < ktiles; ++t) {
        const int k0 = t * 16;
        // stage A: 128 rows x 16 kk via float4 (transpose into As)
        #pragma unroll
        for (int it = 0; it < 2; ++it) {
            int idx = tid + it * 256;          // 0..511
            int r = idx >> 2;                  // 0..127
            int kq = (idx & 3) * 4;            // 0,4,8,12
            int gr = row0 + r, gk = k0 + kq;
            float4 v = {0.f, 0.f, 0.f, 0.f};
            if (gr < M) {
                if (gk + 3 < K) v = *(const float4*)(A + (size_t)gr * K + gk);
                else {
                    float tmp[4] = {0.f, 0.f, 0.f, 0.f};
                    for (int q = 0; q < 4; ++q) if (gk + q < K) tmp[q] = A[(size_t)gr * K + gk + q];
                    v = make_float4(tmp[0], tmp[1], tmp[2], tmp[3]);
                }
            }
            As[kq + 0][r] = v.x; As[kq + 1][r] = v.y;
            As[kq + 2][r] = v.z; As[kq + 3][r] = v.w;
        }
        // stage B: 16 kk x 64 cols, one float4 per thread
        {
            int kk = tid >> 4, c0 = (tid & 15) * 4;
            int gk = k0 + kk;
            float4 v = {0.f, 0.f, 0.f, 0.f};
            if (gk < K) v = *(const float4*)(B + (size_t)gk * 64 + c0);
            *(float4*)&Bs[kk][c0] = v;
        }
        __syncthreads();
        #pragma unroll
        for (int kk = 0; kk < 16; ++kk) {
            float a[8];
            #pragma unroll
            for (int i = 0; i < 8; ++i) a[i] = As[kk][ty * 8 + i];
            float4 bb = *(const float4*)&Bs[kk][tx * 4];
            #pragma unroll
            for (int i = 0; i < 8; ++i) {
                acc[i][0] += a[i] * bb.x; acc[i][1] += a[i] * bb.y;
                acc[i][2] += a[i] * bb.z; acc[i][3] += a[i] * bb.w;
            }
        }
        __syncthreads();
    }
    #pragma unroll
    for (int i = 0; i < 8; ++i) {
        int r = row0 + ty * 8 + i;
        if (r < M)
            *(float4*)(C + (size_t)r * 64 + tx * 4) =
                make_float4(acc[i][0], acc[i][1], acc[i][2], acc[i][3]);
    }
}

// ------------- CSR build: in-degree count -------------
__global__ __launch_bounds__(256) void count_k(const int* __restrict__ ei,
        int* __restrict__ cnt)
{
    int e = blockIdx.x * 256 + threadIdx.x;
    if (e < NE) atomicAdd(&cnt[ei[NE + e]], 1);
}

// ------------- scan stage 1: block-local exclusive scan (1024/block) -------------
__global__ __launch_bounds__(1024) void scan1(const int* __restrict__ cnt,
        int* __restrict__ excl, int* __restrict__ sums)
{
    __shared__ int buf[1024];
    int tid = threadIdx.x;
    int i = blockIdx.x * 1024 + tid;
    int v = (i < NN) ? cnt[i] : 0;
    buf[tid] = v;
    __syncthreads();
    #pragma unroll
    for (int off = 1; off < 1024; off <<= 1) {
        int t = (tid >= off) ? buf[tid - off] : 0;
        __syncthreads();
        buf[tid] += t;
        __syncthreads();
    }
    if (i < NN) excl[i] = buf[tid] - v;
    if (tid == 1023) sums[blockIdx.x] = buf[1023];
}

// ------------- scan stage 2: wave scan over block sums (nb <= 64) -------------
__global__ __launch_bounds__(64) void scan2(int* __restrict__ sums, int nb)
{
    int lane = threadIdx.x;
    int v = (lane < nb) ? sums[lane] : 0;
    int inc = v;
    #pragma unroll
    for (int off = 1; off < 64; off <<= 1) {
        int t = __shfl_up(inc, off);
        if (lane >= off) inc += t;
    }
    if (lane < nb) sums[lane] = inc - v;   // exclusive
}

// ------------- scan stage 3: add block offsets -> rowptr & cursor -------------
__global__ __launch_bounds__(1024) void scan3(const int* __restrict__ excl,
        const int* __restrict__ sums, int* __restrict__ rowptr,
        int* __restrict__ cursor)
{
    int i = blockIdx.x * 1024 + threadIdx.x;
    if (i < NN) {
        int e = excl[i] + sums[blockIdx.x];
        rowptr[i] = e;
        cursor[i] = e;
    }
    if (i == 0) rowptr[NN] = NE;
}

// ------------- CSR build: scatter src into dst-sorted order -------------
__global__ __launch_bounds__(256) void scatter_k(const int* __restrict__ ei,
        int* __restrict__ cursor, int* __restrict__ col)
{
    int e = blockIdx.x * 256 + threadIdx.x;
    if (e < NE) {
        int s = ei[e], d = ei[NE + e];
        int pos = atomicAdd(&cursor[d], 1);
        col[pos] = s;
    }
}

// ------------- per-node logit halves, layer1 (H=8, C=8) -------------
__global__ __launch_bounds__(256) void s_l1(const float* __restrict__ h,
        const float* __restrict__ a_src, const float* __restrict__ a_dst,
        float* __restrict__ s_src, float* __restrict__ s_dst)
{
    int t = blockIdx.x * 256 + threadIdx.x;   // t = n*8 + head
    if (t >= NN * 8) return;
    int n = t >> 3, hd = t & 7;
    const float* hp = h + (size_t)n * 64 + hd * 8;
    float ss = 0.f, sd = 0.f;
    #pragma unroll
    for (int c = 0; c < 8; ++c) {
        float v = hp[c];
        ss += v * a_src[hd * 8 + c];
        sd += v * a_dst[hd * 8 + c];
    }
    s_src[t] = ss;
    s_dst[t] = sd;
}

// ------------- per-node logit halves, layer2 (H=1, C=64) -------------
__global__ __launch_bounds__(256) void s_l2(const float* __restrict__ h,
        const float* __restrict__ a_src, const float* __restrict__ a_dst,
        float* __restrict__ s_src, float* __restrict__ s_dst)
{
    int gid = blockIdx.x * 256 + threadIdx.x;
    int n = gid >> 6;
    int lane = threadIdx.x & 63;
    if (n >= NN) return;
    float v = h[(size_t)n * 64 + lane];
    float ps = v * a_src[lane];
    float pd = v * a_dst[lane];
    #pragma unroll
    for (int off = 32; off > 0; off >>= 1) {
        ps += __shfl_down(ps, off);
        pd += __shfl_down(pd, off);
    }
    if (lane == 0) { s_src[n] = ps; s_dst[n] = pd; }
}

#define LEAKY(s) ((s) > 0.f ? (s) : 0.2f * (s))

// ------------- layer1 aggregation: one wave per dst node, 4-deep MLP -------------
__global__ __launch_bounds__(256) void agg_l1(const int* __restrict__ rowptr,
        const int* __restrict__ col, const float* __restrict__ h,
        const float* __restrict__ ss, const float* __restrict__ sd,
        const float* __restrict__ b, float* __restrict__ out)
{
    int n = (blockIdx.x * 256 + threadIdx.x) >> 6;
    int lane = threadIdx.x & 63;
    if (n >= NN) return;
    int hd = lane >> 3;
    float sdst = sd[n * 8 + hd];
    int r0 = rowptr[n], r1 = rowptr[n + 1];
    float acc = 0.f, dsum = 0.f;
    int i = r0;
    for (; i + 4 <= r1; i += 4) {
        int s0 = col[i], s1 = col[i + 1], s2 = col[i + 2], s3 = col[i + 3];
        float e0 = ss[s0 * 8 + hd], e1 = ss[s1 * 8 + hd];
        float e2 = ss[s2 * 8 + hd], e3 = ss[s3 * 8 + hd];
        float h0 = h[(size_t)s0 * 64 + lane], h1 = h[(size_t)s1 * 64 + lane];
        float h2 = h[(size_t)s2 * 64 + lane], h3 = h[(size_t)s3 * 64 + lane];
        float w0 = __expf(LEAKY(e0 + sdst)), w1 = __expf(LEAKY(e1 + sdst));
        float w2 = __expf(LEAKY(e2 + sdst)), w3 = __expf(LEAKY(e3 + sdst));
        acc += w0 * h0 + w1 * h1 + w2 * h2 + w3 * h3;
        dsum += (w0 + w1) + (w2 + w3);
    }
    for (; i < r1; ++i) {
        int s0 = col[i];
        float w = __expf(LEAKY(ss[s0 * 8 + hd] + sdst));
        acc += w * h[(size_t)s0 * 64 + lane];
        dsum += w;
    }
    float v = acc / (dsum + 1e-16f) + b[lane];
    out[(size_t)n * 64 + lane] = v > 0.f ? v : expm1f(v);   // ELU
}

// ------------- layer2 aggregation: one wave per dst node, 4-deep MLP -------------
__global__ __launch_bounds__(256) void agg_l2(const int* __restrict__ rowptr,
        const int* __restrict__ col, const float* __restrict__ h,
        const float* __restrict__ ss, const float* __restrict__ sd,
        const float* __restrict__ b, float* __restrict__ out)
{
    int n = (blockIdx.x * 256 + threadIdx.x) >> 6;
    int lane = threadIdx.x & 63;
    if (n >= NN) return;
    float sdst = sd[n];
    int r0 = rowptr[n], r1 = rowptr[n + 1];
    float acc = 0.f, dsum = 0.f;
    int i = r0;
    for (; i + 4 <= r1; i += 4) {
        int s0 = col[i], s1 = col[i + 1], s2 = col[i + 2], s3 = col[i + 3];
        float e0 = ss[s0], e1 = ss[s1], e2 = ss[s2], e3 = ss[s3];
        float h0 = h[(size_t)s0 * 64 + lane], h1 = h[(size_t)s1 * 64 + lane];
        float h2 = h[(size_t)s2 * 64 + lane], h3 = h[(size_t)s3 * 64 + lane];
        float w0 = __expf(LEAKY(e0 + sdst)), w1 = __expf(LEAKY(e1 + sdst));
        float w2 = __expf(LEAKY(e2 + sdst)), w3 = __expf(LEAKY(e3 + sdst));
        acc += w0 * h0 + w1 * h1 + w2 * h2 + w3 * h3;
        dsum += (w0 + w1) + (w2 + w3);
    }
    for (; i < r1; ++i) {
        int s0 = col[i];
        float w = __expf(LEAKY(ss[s0] + sdst));
        acc += w * h[(size_t)s0 * 64 + lane];
        dsum += w;
    }
    out[(size_t)n * 64 + lane] = acc / (dsum + 1e-16f) + b[lane];
}

extern "C" void kernel_launch(void* const* d_in, const int* in_sizes, int n_in,
                              void* d_out, int out_size, void* d_ws, size_t ws_size,
                              hipStream_t stream)
{
    const float* x      = (const float*)d_in[0];
    const int*   ei     = (const int*)d_in[1];
    const float* W1     = (const float*)d_in[2];
    const float* a_src1 = (const float*)d_in[3];
    const float* a_dst1 = (const float*)d_in[4];
    const float* b1     = (const float*)d_in[5];
    const float* W2     = (const float*)d_in[6];
    const float* a_src2 = (const float*)d_in[7];
    const float* a_dst2 = (const float*)d_in[8];
    const float* b2     = (const float*)d_in[9];
    float* out = (float*)d_out;

    float* w = (float*)d_ws;
    float* P0     = w;  w += (size_t)NN * 64;       // h1, then h2
    float* P1     = w;  w += (size_t)NN * 64;       // h2in
    float* ss1    = w;  w += (size_t)NN * 8;
    float* sd1    = w;  w += (size_t)NN * 8;
    int* cnt    = (int*)w;  w += NN;
    int* excl   = (int*)w;  w += NN;
    int* sums   = (int*)w;  w += 64;
    int* rowptr = (int*)w;  w += NN + 1;
    int* cursor = (int*)w;  w += NN;
    int* col    = (int*)w;  w += NE;
    float* ss2 = ss1;                                // alias (ss1 dead in layer2)
    float* sd2 = ss1 + NN;

    const int NB = (NN + 1023) / 1024;               // 49 scan blocks

    // ---- CSR build ----
    hipMemsetAsync(cnt, 0, NN * sizeof(int), stream);
    count_k<<<(NE + 255) / 256, 256, 0, stream>>>(ei, cnt);
    scan1<<<NB, 1024, 0, stream>>>(cnt, excl, sums);
    scan2<<<1, 64, 0, stream>>>(sums, NB);
    scan3<<<NB, 1024, 0, stream>>>(excl, sums, rowptr, cursor);
    scatter_k<<<(NE + 255) / 256, 256, 0, stream>>>(ei, cursor, col);

    // ---- layer 1 ----
    gemm128<<<(NN + 127) / 128, 256, 0, stream>>>(x, W1, P0, NN, 300);
    s_l1<<<(NN * 8 + 255) / 256, 256, 0, stream>>>(P0, a_src1, a_dst1, ss1, sd1);
    agg_l1<<<(NN * 64 + 255) / 256, 256, 0, stream>>>(rowptr, col, P0, ss1, sd1, b1, P1);

    // ---- layer 2 ----
    gemm128<<<(NN + 127) / 128, 256, 0, stream>>>(P1, W2, P0, NN, 64);
    s_l2<<<(NN * 64 + 255) / 256, 256, 0, stream>>>(P0, a_src2, a_dst2, ss2, sd2);
    agg_l2<<<(NN * 64 + 255) / 256, 256, 0, stream>>>(rowptr, col, P0, ss2, sd2, b2, out);
}

// Round 5
// 342.147 us; speedup vs baseline: 8.6288x; 1.1513x over previous
//
#include <hip/hip_runtime.h>
#include <math.h>

#define NN 50000
#define NE 1000000

__device__ inline unsigned short f2bf(float f) {          // fp32 -> bf16 RNE
    unsigned u = __float_as_uint(f);
    u += 0x7FFFu + ((u >> 16) & 1u);
    return (unsigned short)(u >> 16);
}
__device__ inline float bf2f(unsigned short s) {
    return __uint_as_float(((unsigned)s) << 16);
}

// ---- GEMM 128x64 fp32 + fused epilogue: bf16 h-store + ss/sd logit halves ----
template <int HEADS>
__global__ __launch_bounds__(256) void gemm_fused(const float* __restrict__ A,
        const float* __restrict__ B, unsigned short* __restrict__ hb,
        const float* __restrict__ asrc, const float* __restrict__ adst,
        float* __restrict__ ss, float* __restrict__ sd, int M, int K)
{
    __shared__ float As[16][132];
    __shared__ float Bs[16][64];
    const int tid = threadIdx.x;
    const int row0 = blockIdx.x * 128;
    const int tx = tid & 15, ty = tid >> 4;
    float acc[8][4] = {};
    const int ktiles = (K + 15) / 16;
    for (int t = 0; t < ktiles; ++t) {
        const int k0 = t * 16;
        #pragma unroll
        for (int it = 0; it < 2; ++it) {
            int idx = tid + it * 256;
            int r = idx >> 2;
            int kq = (idx & 3) * 4;
            int gr = row0 + r, gk = k0 + kq;
            float4 v = {0.f, 0.f, 0.f, 0.f};
            if (gr < M) {
                if (gk + 3 < K) v = *(const float4*)(A + (size_t)gr * K + gk);
                else {
                    float tmp[4] = {0.f, 0.f, 0.f, 0.f};
                    for (int q = 0; q < 4; ++q) if (gk + q < K) tmp[q] = A[(size_t)gr * K + gk + q];
                    v = make_float4(tmp[0], tmp[1], tmp[2], tmp[3]);
                }
            }
            As[kq + 0][r] = v.x; As[kq + 1][r] = v.y;
            As[kq + 2][r] = v.z; As[kq + 3][r] = v.w;
        }
        {
            int kk = tid >> 4, c0 = (tid & 15) * 4;
            int gk = k0 + kk;
            float4 v = {0.f, 0.f, 0.f, 0.f};
            if (gk < K) v = *(const float4*)(B + (size_t)gk * 64 + c0);
            *(float4*)&Bs[kk][c0] = v;
        }
        __syncthreads();
        #pragma unroll
        for (int kk = 0; kk < 16; ++kk) {
            float a[8];
            #pragma unroll
            for (int i = 0; i < 8; ++i) a[i] = As[kk][ty * 8 + i];
            float4 bb = *(const float4*)&Bs[kk][tx * 4];
            #pragma unroll
            for (int i = 0; i < 8; ++i) {
                acc[i][0] += a[i] * bb.x; acc[i][1] += a[i] * bb.y;
                acc[i][2] += a[i] * bb.z; acc[i][3] += a[i] * bb.w;
            }
        }
        __syncthreads();
    }
    // ---- epilogue 1: bf16 store of h ----
    #pragma unroll
    for (int i = 0; i < 8; ++i) {
        int r = row0 + ty * 8 + i;
        if (r < M) {
            ushort4 u;
            u.x = f2bf(acc[i][0]); u.y = f2bf(acc[i][1]);
            u.z = f2bf(acc[i][2]); u.w = f2bf(acc[i][3]);
            *(ushort4*)(hb + (size_t)r * 64 + tx * 4) = u;
        }
    }
    // ---- epilogue 2: logit halves ----
    if (HEADS == 8) {
        int hd = tx >> 1, sub = (tx & 1) * 4;
        #pragma unroll
        for (int i = 0; i < 8; ++i) {
            float pss = 0.f, psd = 0.f;
            #pragma unroll
            for (int q = 0; q < 4; ++q) {
                pss += acc[i][q] * asrc[hd * 8 + sub + q];
                psd += acc[i][q] * adst[hd * 8 + sub + q];
            }
            pss += __shfl_xor(pss, 1);
            psd += __shfl_xor(psd, 1);
            int r = row0 + ty * 8 + i;
            if (!(tx & 1) && r < M) { ss[r * 8 + hd] = pss; sd[r * 8 + hd] = psd; }
        }
    } else {
        #pragma unroll
        for (int i = 0; i < 8; ++i) {
            float p = 0.f, pd = 0.f;
            #pragma unroll
            for (int q = 0; q < 4; ++q) {
                p  += acc[i][q] * asrc[tx * 4 + q];
                pd += acc[i][q] * adst[tx * 4 + q];
            }
            #pragma unroll
            for (int m = 1; m < 16; m <<= 1) {
                p  += __shfl_xor(p, m);
                pd += __shfl_xor(pd, m);
            }
            int r = row0 + ty * 8 + i;
            if (tx == 0 && r < M) { ss[r] = p; sd[r] = pd; }
        }
    }
}

// ------------- CSR: count + per-edge rank (pos) -------------
__global__ __launch_bounds__(256) void count_k(const int* __restrict__ ei,
        int* __restrict__ cnt, int* __restrict__ pos)
{
    int e = blockIdx.x * 256 + threadIdx.x;
    if (e < NE) pos[e] = atomicAdd(&cnt[ei[NE + e]], 1);
}

// ------------- scan stage 1 -------------
__global__ __launch_bounds__(1024) void scan1(const int* __restrict__ cnt,
        int* __restrict__ excl, int* __restrict__ sums)
{
    __shared__ int buf[1024];
    int tid = threadIdx.x;
    int i = blockIdx.x * 1024 + tid;
    int v = (i < NN) ? cnt[i] : 0;
    buf[tid] = v;
    __syncthreads();
    #pragma unroll
    for (int off = 1; off < 1024; off <<= 1) {
        int t = (tid >= off) ? buf[tid - off] : 0;
        __syncthreads();
        buf[tid] += t;
        __syncthreads();
    }
    if (i < NN) excl[i] = buf[tid] - v;
    if (tid == 1023) sums[blockIdx.x] = buf[1023];
}

// ------------- scan stage 2 -------------
__global__ __launch_bounds__(64) void scan2(int* __restrict__ sums, int nb)
{
    int lane = threadIdx.x;
    int v = (lane < nb) ? sums[lane] : 0;
    int inc = v;
    #pragma unroll
    for (int off = 1; off < 64; off <<= 1) {
        int t = __shfl_up(inc, off);
        if (lane >= off) inc += t;
    }
    if (lane < nb) sums[lane] = inc - v;
}

// ------------- scan stage 3 -------------
__global__ __launch_bounds__(1024) void scan3(const int* __restrict__ excl,
        const int* __restrict__ sums, int* __restrict__ rowptr)
{
    int i = blockIdx.x * 1024 + threadIdx.x;
    if (i < NN) rowptr[i] = excl[i] + sums[blockIdx.x];
    if (i == 0) rowptr[NN] = NE;
}

// ------------- CSR: scatter (no atomic; nontemporal store) -------------
__global__ __launch_bounds__(256) void scatter_k(const int* __restrict__ ei,
        const int* __restrict__ rowptr, const int* __restrict__ pos,
        int* __restrict__ col)
{
    int e = blockIdx.x * 256 + threadIdx.x;
    if (e < NE) {
        int s = ei[e], d = ei[NE + e];
        __builtin_nontemporal_store(s, &col[rowptr[d] + pos[e]]);
    }
}

#define LEAKY(s) ((s) > 0.f ? (s) : 0.2f * (s))

// ------------- layer1 agg: wave/node, bf16 h gather, fused norm+bias+ELU -------------
__global__ __launch_bounds__(256) void agg_l1(const int* __restrict__ rowptr,
        const int* __restrict__ col, const unsigned short* __restrict__ hb,
        const float* __restrict__ ss, const float* __restrict__ sd,
        const float* __restrict__ b, float* __restrict__ out)
{
    int n = (blockIdx.x * 256 + threadIdx.x) >> 6;
    int lane = threadIdx.x & 63;
    if (n >= NN) return;
    int hd = lane >> 3;
    float sdst = sd[n * 8 + hd];
    int r0 = rowptr[n], r1 = rowptr[n + 1];
    float acc = 0.f, dsum = 0.f;
    int i = r0;
    for (; i + 4 <= r1; i += 4) {
        int s0 = col[i], s1 = col[i + 1], s2 = col[i + 2], s3 = col[i + 3];
        float e0 = ss[s0 * 8 + hd], e1 = ss[s1 * 8 + hd];
        float e2 = ss[s2 * 8 + hd], e3 = ss[s3 * 8 + hd];
        float h0 = bf2f(hb[(size_t)s0 * 64 + lane]), h1 = bf2f(hb[(size_t)s1 * 64 + lane]);
        float h2 = bf2f(hb[(size_t)s2 * 64 + lane]), h3 = bf2f(hb[(size_t)s3 * 64 + lane]);
        float w0 = __expf(LEAKY(e0 + sdst)), w1 = __expf(LEAKY(e1 + sdst));
        float w2 = __expf(LEAKY(e2 + sdst)), w3 = __expf(LEAKY(e3 + sdst));
        acc += w0 * h0 + w1 * h1 + w2 * h2 + w3 * h3;
        dsum += (w0 + w1) + (w2 + w3);
    }
    for (; i < r1; ++i) {
        int s0 = col[i];
        float w = __expf(LEAKY(ss[s0 * 8 + hd] + sdst));
        acc += w * bf2f(hb[(size_t)s0 * 64 + lane]);
        dsum += w;
    }
    float v = acc / (dsum + 1e-16f) + b[lane];
    out[(size_t)n * 64 + lane] = v > 0.f ? v : expm1f(v);   // ELU
}

// ------------- layer2 agg: wave/node, bf16 h gather, fused norm+bias -------------
__global__ __launch_bounds__(256) void agg_l2(const int* __restrict__ rowptr,
        const int* __restrict__ col, const unsigned short* __restrict__ hb,
        const float* __restrict__ ss, const float* __restrict__ sd,
        const float* __restrict__ b, float* __restrict__ out)
{
    int n = (blockIdx.x * 256 + threadIdx.x) >> 6;
    int lane = threadIdx.x & 63;
    if (n >= NN) return;
    float sdst = sd[n];
    int r0 = rowptr[n], r1 = rowptr[n + 1];
    float acc = 0.f, dsum = 0.f;
    int i = r0;
    for (; i + 4 <= r1; i += 4) {
        int s0 = col[i], s1 = col[i + 1], s2 = col[i + 2], s3 = col[i + 3];
        float e0 = ss[s0], e1 = ss[s1], e2 = ss[s2], e3 = ss[s3];
        float h0 = bf2f(hb[(size_t)s0 * 64 + lane]), h1 = bf2f(hb[(size_t)s1 * 64 + lane]);
        float h2 = bf2f(hb[(size_t)s2 * 64 + lane]), h3 = bf2f(hb[(size_t)s3 * 64 + lane]);
        float w0 = __expf(LEAKY(e0 + sdst)), w1 = __expf(LEAKY(e1 + sdst));
        float w2 = __expf(LEAKY(e2 + sdst)), w3 = __expf(LEAKY(e3 + sdst));
        acc += w0 * h0 + w1 * h1 + w2 * h2 + w3 * h3;
        dsum += (w0 + w1) + (w2 + w3);
    }
    for (; i < r1; ++i) {
        int s0 = col[i];
        float w = __expf(LEAKY(ss[s0] + sdst));
        acc += w * bf2f(hb[(size_t)s0 * 64 + lane]);
        dsum += w;
    }
    out[(size_t)n * 64 + lane] = acc / (dsum + 1e-16f) + b[lane];
}

extern "C" void kernel_launch(void* const* d_in, const int* in_sizes, int n_in,
                              void* d_out, int out_size, void* d_ws, size_t ws_size,
                              hipStream_t stream)
{
    const float* x      = (const float*)d_in[0];
    const int*   ei     = (const int*)d_in[1];
    const float* W1     = (const float*)d_in[2];
    const float* a_src1 = (const float*)d_in[3];
    const float* a_dst1 = (const float*)d_in[4];
    const float* b1     = (const float*)d_in[5];
    const float* W2     = (const float*)d_in[6];
    const float* a_src2 = (const float*)d_in[7];
    const float* a_dst2 = (const float*)d_in[8];
    const float* b2     = (const float*)d_in[9];
    float* out = (float*)d_out;

    // workspace: h_bf first (8B-aligned for ushort4 stores)
    char* wp = (char*)d_ws;
    unsigned short* hb = (unsigned short*)wp;  wp += (size_t)NN * 64 * 2;   // h1 then h2 (bf16)
    float* P1  = (float*)wp;  wp += (size_t)NN * 64 * 4;                    // h2in (fp32)
    float* ss1 = (float*)wp;  wp += (size_t)NN * 8 * 4;
    float* sd1 = (float*)wp;  wp += (size_t)NN * 8 * 4;
    int* cnt    = (int*)wp;  wp += (size_t)NN * 4;
    int* excl   = (int*)wp;  wp += (size_t)NN * 4;
    int* sums   = (int*)wp;  wp += 64 * 4;
    int* rowptr = (int*)wp;  wp += (size_t)(NN + 1) * 4;
    int* pos    = (int*)wp;  wp += (size_t)NE * 4;
    int* col    = (int*)wp;  wp += (size_t)NE * 4;
    float* ss2 = ss1;                     // alias (layer1 logits dead in layer2)
    float* sd2 = ss1 + NN;

    const int NB = (NN + 1023) / 1024;

    // ---- CSR build ----
    hipMemsetAsync(cnt, 0, NN * sizeof(int), stream);
    count_k<<<(NE + 255) / 256, 256, 0, stream>>>(ei, cnt, pos);
    scan1<<<NB, 1024, 0, stream>>>(cnt, excl, sums);
    scan2<<<1, 64, 0, stream>>>(sums, NB);
    scan3<<<NB, 1024, 0, stream>>>(excl, sums, rowptr);
    scatter_k<<<(NE + 255) / 256, 256, 0, stream>>>(ei, rowptr, pos, col);

    // ---- layer 1 ----
    gemm_fused<8><<<(NN + 127) / 128, 256, 0, stream>>>(x, W1, hb, a_src1, a_dst1, ss1, sd1, NN, 300);
    agg_l1<<<(NN * 64 + 255) / 256, 256, 0, stream>>>(rowptr, col, hb, ss1, sd1, b1, P1);

    // ---- layer 2 ----
    gemm_fused<1><<<(NN + 127) / 128, 256, 0, stream>>>(P1, W2, hb, a_src2, a_dst2, ss2, sd2, NN, 64);
    agg_l2<<<(NN * 64 + 255) / 256, 256, 0, stream>>>(rowptr, col, hb, ss2, sd2, b2, out);
}

// Round 7
// 310.124 us; speedup vs baseline: 9.5198x; 1.1033x over previous
//
#include <hip/hip_runtime.h>
#include <math.h>

#define NN 50000
#define NE 1000000

typedef __bf16 bf16x8 __attribute__((ext_vector_type(8)));
typedef float f32x4 __attribute__((ext_vector_type(4)));

__device__ inline unsigned short f2bf(float f) {          // fp32 -> bf16 RNE
    unsigned u = __float_as_uint(f);
    u += 0x7FFFu + ((u >> 16) & 1u);
    return (unsigned short)(u >> 16);
}
__device__ inline float bf2f(unsigned short s) {
    return __uint_as_float(((unsigned)s) << 16);
}

// ---- prep: W1 -> Bt1[64][320] bf16 (zero-pad k>=300), W2 -> Bt2[64][64] bf16 ----
__global__ __launch_bounds__(256) void prep_B(const float* __restrict__ W1,
        const float* __restrict__ W2, unsigned short* __restrict__ Bt1,
        unsigned short* __restrict__ Bt2)
{
    int t = blockIdx.x * 256 + threadIdx.x;        // grid = 96 blocks = 24576 exactly
    if (t < 64 * 320) {
        int c = t / 320, k = t % 320;
        Bt1[t] = (k < 300) ? f2bf(W1[k * 64 + c]) : (unsigned short)0;
    } else {
        int i = t - 64 * 320;
        int c = i >> 6, k = i & 63;
        Bt2[i] = f2bf(W2[k * 64 + c]);
    }
}

// ---- MFMA GEMM: C[M,64] = A[M,K] @ B, bf16 mfma, fused bf16-h store + logits ----
template <int HEADS, bool A_IS_F32>
__global__ __launch_bounds__(256) void gemm_mfma(const void* __restrict__ Av,
        const unsigned short* __restrict__ Bt,    // [64][KT*32] bf16
        unsigned short* __restrict__ hb,
        const float* __restrict__ asrc, const float* __restrict__ adst,
        float* __restrict__ ss, float* __restrict__ sd,
        int M, int K, int KT)
{
    __shared__ unsigned short lds[5120];           // As[64][40] | Bs[64][40]; reused as Ct
    const int tid  = threadIdx.x;
    const int row0 = blockIdx.x * 64;
    const int lane = tid & 63, w = tid >> 6;
    const int quad = lane >> 4, mm = lane & 15;
    const int sr = tid >> 2, q8 = (tid & 3) * 8;   // staging row / k-octet
    const int gsr = row0 + sr;

    f32x4 acc[4];
    #pragma unroll
    for (int i = 0; i < 4; ++i) acc[i] = (f32x4){0.f, 0.f, 0.f, 0.f};

    const int Kpad = KT * 32;
    for (int kt = 0; kt < KT; ++kt) {
        const int k0 = kt * 32;
        // ---- stage A (64 x 32) ----
        int4 apack = {0, 0, 0, 0};
        if (gsr < M) {
            if (A_IS_F32) {
                const float* A = (const float*)Av;
                const float* ap = A + (size_t)gsr * K + k0 + q8;
                unsigned short* up = (unsigned short*)&apack;
                if (k0 + q8 + 7 < K) {
                    float4 v0 = *(const float4*)ap;
                    float4 v1 = *(const float4*)(ap + 4);
                    up[0]=f2bf(v0.x); up[1]=f2bf(v0.y); up[2]=f2bf(v0.z); up[3]=f2bf(v0.w);
                    up[4]=f2bf(v1.x); up[5]=f2bf(v1.y); up[6]=f2bf(v1.z); up[7]=f2bf(v1.w);
                } else {
                    #pragma unroll
                    for (int j = 0; j < 8; ++j)
                        up[j] = (k0 + q8 + j < K) ? f2bf(ap[j]) : (unsigned short)0;
                }
            } else {
                const unsigned short* A = (const unsigned short*)Av;
                apack = *(const int4*)(A + (size_t)gsr * K + k0 + q8);
            }
        }
        *(int4*)(lds + sr * 40 + q8) = apack;
        // ---- stage B (64 cols x 32 k) from pre-transposed Bt: direct copy ----
        *(int4*)(lds + 2560 + sr * 40 + q8) =
            *(const int4*)(Bt + (size_t)sr * Kpad + k0 + q8);
        __syncthreads();
        // ---- MFMA: A[m=lane&15][k=quad*8+j], B[k=quad*8+j][n=lane&15] ----
        bf16x8 af = *(const bf16x8*)(lds + (w * 16 + mm) * 40 + quad * 8);
        #pragma unroll
        for (int nt = 0; nt < 4; ++nt) {
            bf16x8 bfv = *(const bf16x8*)(lds + 2560 + (nt * 16 + mm) * 40 + quad * 8);
            acc[nt] = __builtin_amdgcn_mfma_f32_16x16x32_bf16(af, bfv, acc[nt], 0, 0, 0);
        }
        __syncthreads();
    }
    // ---- epilogue: C (col=lane&15, row=quad*4+reg) -> LDS bf16 tile ----
    #pragma unroll
    for (int nt = 0; nt < 4; ++nt)
        #pragma unroll
        for (int reg = 0; reg < 4; ++reg)
            lds[w * 1152 + (quad * 4 + reg) * 72 + nt * 16 + mm] = f2bf(acc[nt][reg]);
    __syncthreads();
    // coalesced bf16 h store: 16 shorts (32 B) per thread = TWO int4 stores
    const int cg = (tid & 3) * 16;
    const unsigned short* crow = lds + (sr >> 4) * 1152 + (sr & 15) * 72;
    if (gsr < M) {
        *(int4*)(hb + (size_t)gsr * 64 + cg)     = *(const int4*)(crow + cg);
        *(int4*)(hb + (size_t)gsr * 64 + cg + 8) = *(const int4*)(crow + cg + 8);
    }
    if (HEADS == 8) {
        #pragma unroll
        for (int hh = 0; hh < 2; ++hh) {
            int hd = (tid & 3) + hh * 4;
            float pss = 0.f, psd = 0.f;
            #pragma unroll
            for (int c = 0; c < 8; ++c) {
                float hv = bf2f(crow[hd * 8 + c]);
                pss += hv * asrc[hd * 8 + c];
                psd += hv * adst[hd * 8 + c];
            }
            if (gsr < M) { ss[gsr * 8 + hd] = pss; sd[gsr * 8 + hd] = psd; }
        }
    } else {
        int p = tid & 3;
        float pss = 0.f, psd = 0.f;
        #pragma unroll
        for (int c = 0; c < 16; ++c) {
            float hv = bf2f(crow[p * 16 + c]);
            pss += hv * asrc[p * 16 + c];
            psd += hv * adst[p * 16 + c];
        }
        pss += __shfl_xor(pss, 1); psd += __shfl_xor(psd, 1);
        pss += __shfl_xor(pss, 2); psd += __shfl_xor(psd, 2);
        if (p == 0 && gsr < M) { ss[gsr] = pss; sd[gsr] = psd; }
    }
}

// ------------- CSR: count + per-edge rank (pos) -------------
__global__ __launch_bounds__(256) void count_k(const int* __restrict__ ei,
        int* __restrict__ cnt, int* __restrict__ pos)
{
    int e = blockIdx.x * 256 + threadIdx.x;
    if (e < NE) pos[e] = atomicAdd(&cnt[ei[NE + e]], 1);
}

// ------------- scan stage 1 -------------
__global__ __launch_bounds__(1024) void scan1(const int* __restrict__ cnt,
        int* __restrict__ excl, int* __restrict__ sums)
{
    __shared__ int buf[1024];
    int tid = threadIdx.x;
    int i = blockIdx.x * 1024 + tid;
    int v = (i < NN) ? cnt[i] : 0;
    buf[tid] = v;
    __syncthreads();
    #pragma unroll
    for (int off = 1; off < 1024; off <<= 1) {
        int t = (tid >= off) ? buf[tid - off] : 0;
        __syncthreads();
        buf[tid] += t;
        __syncthreads();
    }
    if (i < NN) excl[i] = buf[tid] - v;
    if (tid == 1023) sums[blockIdx.x] = buf[1023];
}

// ------------- scan stage 2 -------------
__global__ __launch_bounds__(64) void scan2(int* __restrict__ sums, int nb)
{
    int lane = threadIdx.x;
    int v = (lane < nb) ? sums[lane] : 0;
    int inc = v;
    #pragma unroll
    for (int off = 1; off < 64; off <<= 1) {
        int t = __shfl_up(inc, off);
        if (lane >= off) inc += t;
    }
    if (lane < nb) sums[lane] = inc - v;
}

// ------------- scan stage 3 -------------
__global__ __launch_bounds__(1024) void scan3(const int* __restrict__ excl,
        const int* __restrict__ sums, int* __restrict__ rowptr)
{
    int i = blockIdx.x * 1024 + threadIdx.x;
    if (i < NN) rowptr[i] = excl[i] + sums[blockIdx.x];
    if (i == 0) rowptr[NN] = NE;
}

// ------------- CSR: scatter (no atomic; nontemporal store) -------------
__global__ __launch_bounds__(256) void scatter_k(const int* __restrict__ ei,
        const int* __restrict__ rowptr, const int* __restrict__ pos,
        int* __restrict__ col)
{
    int e = blockIdx.x * 256 + threadIdx.x;
    if (e < NE) {
        int s = ei[e], d = ei[NE + e];
        __builtin_nontemporal_store(s, &col[rowptr[d] + pos[e]]);
    }
}

#define LEAKY(s) ((s) > 0.f ? (s) : 0.2f * (s))

// ------------- layer1 agg: wave/node, bf16 gather, fused norm+bias+ELU, bf16 out -------------
__global__ __launch_bounds__(256) void agg_l1(const int* __restrict__ rowptr,
        const int* __restrict__ col, const unsigned short* __restrict__ hb,
        const float* __restrict__ ss, const float* __restrict__ sd,
        const float* __restrict__ b, unsigned short* __restrict__ out)
{
    int n = (blockIdx.x * 256 + threadIdx.x) >> 6;
    int lane = threadIdx.x & 63;
    if (n >= NN) return;
    int hd = lane >> 3;
    float sdst = sd[n * 8 + hd];
    int r0 = rowptr[n], r1 = rowptr[n + 1];
    float acc = 0.f, dsum = 0.f;
    int i = r0;
    for (; i + 4 <= r1; i += 4) {
        int s0 = col[i], s1 = col[i + 1], s2 = col[i + 2], s3 = col[i + 3];
        float e0 = ss[s0 * 8 + hd], e1 = ss[s1 * 8 + hd];
        float e2 = ss[s2 * 8 + hd], e3 = ss[s3 * 8 + hd];
        float h0 = bf2f(hb[(size_t)s0 * 64 + lane]), h1 = bf2f(hb[(size_t)s1 * 64 + lane]);
        float h2 = bf2f(hb[(size_t)s2 * 64 + lane]), h3 = bf2f(hb[(size_t)s3 * 64 + lane]);
        float w0 = __expf(LEAKY(e0 + sdst)), w1 = __expf(LEAKY(e1 + sdst));
        float w2 = __expf(LEAKY(e2 + sdst)), w3 = __expf(LEAKY(e3 + sdst));
        acc += w0 * h0 + w1 * h1 + w2 * h2 + w3 * h3;
        dsum += (w0 + w1) + (w2 + w3);
    }
    for (; i < r1; ++i) {
        int s0 = col[i];
        float w = __expf(LEAKY(ss[s0 * 8 + hd] + sdst));
        acc += w * bf2f(hb[(size_t)s0 * 64 + lane]);
        dsum += w;
    }
    float v = acc / (dsum + 1e-16f) + b[lane];
    out[(size_t)n * 64 + lane] = f2bf(v > 0.f ? v : expm1f(v));   // ELU, bf16
}

// ------------- layer2 agg: wave/node, bf16 gather, fused norm+bias, fp32 out -------------
__global__ __launch_bounds__(256) void agg_l2(const int* __restrict__ rowptr,
        const int* __restrict__ col, const unsigned short* __restrict__ hb,
        const float* __restrict__ ss, const float* __restrict__ sd,
        const float* __restrict__ b, float* __restrict__ out)
{
    int n = (blockIdx.x * 256 + threadIdx.x) >> 6;
    int lane = threadIdx.x & 63;
    if (n >= NN) return;
    float sdst = sd[n];
    int r0 = rowptr[n], r1 = rowptr[n + 1];
    float acc = 0.f, dsum = 0.f;
    int i = r0;
    for (; i + 4 <= r1; i += 4) {
        int s0 = col[i], s1 = col[i + 1], s2 = col[i + 2], s3 = col[i + 3];
        float e0 = ss[s0], e1 = ss[s1], e2 = ss[s2], e3 = ss[s3];
        float h0 = bf2f(hb[(size_t)s0 * 64 + lane]), h1 = bf2f(hb[(size_t)s1 * 64 + lane]);
        float h2 = bf2f(hb[(size_t)s2 * 64 + lane]), h3 = bf2f(hb[(size_t)s3 * 64 + lane]);
        float w0 = __expf(LEAKY(e0 + sdst)), w1 = __expf(LEAKY(e1 + sdst));
        float w2 = __expf(LEAKY(e2 + sdst)), w3 = __expf(LEAKY(e3 + sdst));
        acc += w0 * h0 + w1 * h1 + w2 * h2 + w3 * h3;
        dsum += (w0 + w1) + (w2 + w3);
    }
    for (; i < r1; ++i) {
        int s0 = col[i];
        float w = __expf(LEAKY(ss[s0] + sdst));
        acc += w * bf2f(hb[(size_t)s0 * 64 + lane]);
        dsum += w;
    }
    out[(size_t)n * 64 + lane] = acc / (dsum + 1e-16f) + b[lane];
}

extern "C" void kernel_launch(void* const* d_in, const int* in_sizes, int n_in,
                              void* d_out, int out_size, void* d_ws, size_t ws_size,
                              hipStream_t stream)
{
    const float* x      = (const float*)d_in[0];
    const int*   ei     = (const int*)d_in[1];
    const float* W1     = (const float*)d_in[2];
    const float* a_src1 = (const float*)d_in[3];
    const float* a_dst1 = (const float*)d_in[4];
    const float* b1     = (const float*)d_in[5];
    const float* W2     = (const float*)d_in[6];
    const float* a_src2 = (const float*)d_in[7];
    const float* a_dst2 = (const float*)d_in[8];
    const float* b2     = (const float*)d_in[9];
    float* out = (float*)d_out;

    // workspace (16B-aligned blocks first)
    char* wp = (char*)d_ws;
    unsigned short* hb  = (unsigned short*)wp;  wp += (size_t)NN * 64 * 2;  // h1 then h2 (bf16)
    unsigned short* P1b = (unsigned short*)wp;  wp += (size_t)NN * 64 * 2;  // h2in (bf16)
    unsigned short* Bt1 = (unsigned short*)wp;  wp += (size_t)64 * 320 * 2; // W1^T bf16 padded
    unsigned short* Bt2 = (unsigned short*)wp;  wp += (size_t)64 * 64 * 2;  // W2^T bf16
    float* ss1 = (float*)wp;  wp += (size_t)NN * 8 * 4;
    float* sd1 = (float*)wp;  wp += (size_t)NN * 8 * 4;
    int* cnt    = (int*)wp;  wp += (size_t)NN * 4;
    int* excl   = (int*)wp;  wp += (size_t)NN * 4;
    int* sums   = (int*)wp;  wp += 64 * 4;
    int* rowptr = (int*)wp;  wp += (size_t)(NN + 1) * 4;
    int* pos    = (int*)wp;  wp += (size_t)NE * 4;
    int* col    = (int*)wp;  wp += (size_t)NE * 4;
    float* ss2 = ss1;                    // alias (layer1 logits dead in layer2)
    float* sd2 = ss1 + NN;

    const int NB = (NN + 1023) / 1024;

    // ---- CSR build + weight prep ----
    hipMemsetAsync(cnt, 0, NN * sizeof(int), stream);
    count_k<<<(NE + 255) / 256, 256, 0, stream>>>(ei, cnt, pos);
    scan1<<<NB, 1024, 0, stream>>>(cnt, excl, sums);
    scan2<<<1, 64, 0, stream>>>(sums, NB);
    scan3<<<NB, 1024, 0, stream>>>(excl, sums, rowptr);
    scatter_k<<<(NE + 255) / 256, 256, 0, stream>>>(ei, rowptr, pos, col);
    prep_B<<<96, 256, 0, stream>>>(W1, W2, Bt1, Bt2);

    // ---- layer 1 ----
    gemm_mfma<8, true><<<(NN + 63) / 64, 256, 0, stream>>>(
        x, Bt1, hb, a_src1, a_dst1, ss1, sd1, NN, 300, 10);
    agg_l1<<<(NN * 64 + 255) / 256, 256, 0, stream>>>(rowptr, col, hb, ss1, sd1, b1, P1b);

    // ---- layer 2 ----
    gemm_mfma<1, false><<<(NN + 63) / 64, 256, 0, stream>>>(
        P1b, Bt2, hb, a_src2, a_dst2, ss2, sd2, NN, 64, 2);
    agg_l2<<<(NN * 64 + 255) / 256, 256, 0, stream>>>(rowptr, col, hb, ss2, sd2, b2, out);
}